// Round 11
// baseline (378.066 us; speedup 1.0000x reference)
//
#include <hip/hip_runtime.h>
#include <hip/hip_bf16.h>

constexpr int NB   = 2;
constexpr int LL   = 512;
constexpr int FF   = 128;
constexpr int CC   = 64;
constexpr int HH   = 12;
constexpr int DD   = 16;
constexpr int HD   = HH * DD;      // 192
constexpr int FEAT = HH*CC + HH*DD + HH*7;  // 1044
constexpr float INFV   = 100000.0f;
constexpr float SCALEF = 0.57735026918962576f;   // sqrt(1/3)
constexpr float SQ29H  = 0.23570226039551584f;   // sqrt(2/9)/2

// ---------------- kernel 1: q/k/v projections, W streamed via LDS ----------------
// k stored as kT4[n][hd/4][j][4]: for each lane j, its 4 consecutive k-values are
// contiguous -> phase-1 reads one float4 per hd4 (coalesced dwordx4, 1KB/wave).
// v stored transposed vT[n][hd][j] (phase-2a float4 along j).
__global__ __launch_bounds__(192) void qkv_kernel(
    const float* __restrict__ xg, const float* __restrict__ Wq,
    const float* __restrict__ Wk, const float* __restrict__ Wv,
    float* __restrict__ q_ws, float* __restrict__ kT4, float* __restrict__ vT)
{
    const int row = blockIdx.x;
    const int n = row >> 9, i = row & 511;
    const int t = threadIdx.x;
    __shared__ __align__(16) float sx[FF];
    __shared__ __align__(16) float sw[3*HD*20];   // 45 KB

    if (t < FF) sx[t] = xg[(size_t)row*FF + t];

    float aq = 0.f, ak = 0.f, av = 0.f;
    for (int ft = 0; ft < 8; ++ft) {
        __syncthreads();
        #pragma unroll
        for (int m = 0; m < 3; ++m) {
            const float* W = (m == 0) ? Wq : ((m == 1) ? Wk : Wv);
            #pragma unroll
            for (int p = 0; p < 4; ++p) {
                const int r = (t >> 2) + 48*p, q = t & 3;
                float4 v = *(const float4*)(W + (size_t)r*FF + ft*16 + q*4);
                *(float4*)&sw[m*3840 + r*20 + q*4] = v;
            }
        }
        __syncthreads();
        const float* xf = &sx[ft*16];
        const float* wq = &sw[0*3840 + t*20];
        const float* wk = &sw[1*3840 + t*20];
        const float* wv = &sw[2*3840 + t*20];
        #pragma unroll
        for (int f4 = 0; f4 < 4; ++f4) {
            float4 xv = *(const float4*)&xf[f4*4];
            float4 a = *(const float4*)&wq[f4*4];
            float4 b = *(const float4*)&wk[f4*4];
            float4 c = *(const float4*)&wv[f4*4];
            aq += xv.x*a.x + xv.y*a.y + xv.z*a.z + xv.w*a.w;
            ak += xv.x*b.x + xv.y*b.y + xv.z*b.z + xv.w*b.w;
            av += xv.x*c.x + xv.y*c.y + xv.z*c.z + xv.w*c.w;
        }
    }
    q_ws[(size_t)row*HD + t] = aq;
    kT4[(((size_t)n*48 + (t >> 2))*LL + i)*4 + (t & 3)] = ak;
    vT[((size_t)n*HD + t)*LL + i] = av;
}

// ---------------- kernel 2: fused attention, 512 threads/block ----------------
__global__ __launch_bounds__(512, 2) void attn_kernel(
    const float* __restrict__ Rg, const float* __restrict__ tg, const float* __restrict__ pg,
    const float* __restrict__ xg, const float* __restrict__ zg, const int* __restrict__ maskg,
    const float* __restrict__ Wpbg, const float* __restrict__ gammag,
    const float* __restrict__ Woutg, const float* __restrict__ boutg,
    const float* __restrict__ lnwg, const float* __restrict__ lnbg,
    const float* __restrict__ q_ws, const float* __restrict__ kT4, const float* __restrict__ vT,
    float* __restrict__ outg)
{
    const int row = blockIdx.x;          // n*LL + i
    const int n = row >> 9;
    const int tid = threadIdx.x;

    __shared__ __align__(16) float s_exp[HH*LL];   // 24 KB  exp(logits), h-major
    __shared__ __align__(16) float s_big[4*768];   // 12 KB  wpb (phase1) / 2b partials / p4 partials
    __shared__ __align__(16) float s_q[HD];
    __shared__ __align__(16) float s_x[FF];
    __shared__ __align__(16) float s_y[FF];
    __shared__ __align__(16) float s_f[FEAT];
    __shared__ float s_aggr[36];
    __shared__ float s_inv[HH];
    __shared__ float s_coef[HH];
    __shared__ float s_geo[15];   // p_i[3], t[3], R[9]
    __shared__ float s_red[2];

    if (tid < FF) s_x[tid] = xg[(size_t)row*FF + tid];
    if (tid >= 128 && tid < 128 + HD) s_q[tid-128] = q_ws[(size_t)row*HD + (tid-128)];
    for (int o = tid; o < HH*CC; o += 512) s_big[o] = Wpbg[o];   // wpb staged in s_big
    if (tid >= 320 && tid < 332) {
        float g = gammag[tid-320];
        float gamma = log1pf(__expf(fminf(g, 80.0f)));   // softplus
        s_coef[tid-320] = -gamma * SQ29H;
    }
    if (tid >= 332 && tid < 335) s_geo[tid-332] = pg[(size_t)row*3 + (tid-332)];
    if (tid >= 335 && tid < 338) s_geo[3 + tid-335] = tg[(size_t)row*3 + (tid-335)];
    if (tid >= 338 && tid < 347) s_geo[6 + tid-338] = Rg[(size_t)row*9 + (tid-338)];
    const int mi = maskg[row];   // block-uniform
    __syncthreads();

    if (mi) {
        // ---- phase 1: exp(logits), one j per thread; acc[12], z read ONCE ----
        {
            const int j = tid;
            float acc[HH];
            #pragma unroll
            for (int h = 0; h < HH; ++h) acc[h] = 0.f;

            // z . Wpb : z chunk consumed immediately against LDS broadcasts
            const float* zr = zg + ((size_t)row*LL + j)*CC;
            #pragma unroll
            for (int c4 = 0; c4 < CC/4; ++c4) {
                float4 zv = *(const float4*)(zr + c4*4);
                #pragma unroll
                for (int h = 0; h < HH; ++h) {
                    float4 w = *(const float4*)&s_big[h*CC + c4*4];   // broadcast
                    acc[h] += zv.x*w.x + zv.y*w.y + zv.z*w.z + zv.w*w.w;
                }
            }
            // q . k : kT4 -> one coalesced float4 per hd4 (48 dwordx4 total)
            const float* kb = kT4 + ((size_t)(n*48)*LL + j)*4;
            #pragma unroll
            for (int hd4 = 0; hd4 < HD/4; ++hd4) {
                float4 q4 = *(const float4*)&s_q[hd4*4];
                float4 k4 = *(const float4*)(kb + (size_t)hd4*LL*4);
                acc[hd4 >> 2] += q4.x*k4.x + q4.y*k4.y + q4.z*k4.z + q4.w*k4.w;
            }
            const float* pj = pg + ((size_t)n*LL + j)*3;
            float e0 = s_geo[0]-pj[0];
            float e1 = s_geo[1]-pj[1];
            float e2 = s_geo[2]-pj[2];
            float d2 = e0*e0 + e1*e1 + e2*e2;
            const float sub = maskg[n*LL + j] ? 0.0f : INFV;
            #pragma unroll
            for (int h = 0; h < HH; ++h) {
                float lg = (acc[h] + d2*s_coef[h]) * SCALEF - sub;
                s_exp[h*LL + j] = __expf(fminf(lg, 80.0f));
            }
        }
        __syncthreads();

        // ---- per-head sums -> reciprocals ----
        {
            const int wv = tid >> 6, lane = tid & 63;
            for (int h = wv; h < HH; h += 8) {
                float s = 0.f;
                #pragma unroll
                for (int r = 0; r < 8; ++r) s += s_exp[h*LL + lane + (r<<6)];
                #pragma unroll
                for (int off = 32; off > 0; off >>= 1) s += __shfl_xor(s, off, 64);
                if (lane == 0) s_inv[h] = 1.0f / fmaxf(s, 1e-30f);
            }
        }
        __syncthreads();

        // ---- phases 2a + 2b CONCURRENT on disjoint waves ----
        {
            const int wv = tid >> 6, lane = tid & 63;
            if (wv < 4) {
                // 2b: feat_p2n partials; wave q4v = j-chunk of 128, lane = c.
                // 4-j steps with float4 ep broadcasts: 384 ds_read_b128 vs 1536 b32.
                const int c = lane, q4v = wv;
                float acc[HH];
                #pragma unroll
                for (int h = 0; h < HH; ++h) acc[h] = 0.f;
                const float* zb = zg + ((size_t)row*LL + q4v*128)*CC + c;
                const float* ep = s_exp + q4v*128;
                for (int jj = 0; jj < 128; jj += 4) {
                    float z0 = zb[(size_t)(jj+0)*CC];
                    float z1 = zb[(size_t)(jj+1)*CC];
                    float z2 = zb[(size_t)(jj+2)*CC];
                    float z3 = zb[(size_t)(jj+3)*CC];
                    #pragma unroll
                    for (int h = 0; h < HH; ++h) {
                        float4 e = *(const float4*)&ep[h*LL + jj];   // broadcast b128
                        acc[h] += e.x*z0 + e.y*z1 + e.z*z2 + e.w*z3;
                    }
                }
                #pragma unroll
                for (int h = 0; h < HH; ++h) s_big[q4v*768 + h*64 + c] = acc[h];
            } else if (tid < 448) {
                // 2a: feat_node, hd = tid-256, full-j float4 (vT)
                const int hd = tid - 256;
                const float* vb = vT + ((size_t)n*HD + hd)*LL;
                const float* ep = s_exp + (hd >> 4)*LL;
                float a = 0.f;
                #pragma unroll 2
                for (int j4 = 0; j4 < 128; ++j4) {
                    float4 vv = *(const float4*)(vb + j4*4);
                    float4 av = *(const float4*)(ep + j4*4);
                    a += vv.x*av.x + vv.y*av.y + vv.z*av.z + vv.w*av.w;
                }
                s_f[768 + hd] = a * s_inv[hd >> 4];
            } else {
                // alpha . p_CB: 36 outputs on wave 7
                const int o = tid - 448;
                if (o < 36) {
                    const int h = o / 3, ax = o - h*3;
                    const float* pb = pg + (size_t)n*LL*3 + ax;
                    const float* ep = s_exp + h*LL;
                    float a = 0.f;
                    #pragma unroll 4
                    for (int j = 0; j < LL; ++j) a += ep[j] * pb[(size_t)j*3];
                    s_aggr[o] = a * s_inv[h];
                }
            }
        }
        __syncthreads();

        // ---- 2b reduce + phase 3 ----
        for (int o = tid; o < 768; o += 512)
            s_f[o] = (s_big[o] + s_big[768+o] + s_big[1536+o] + s_big[2304+o]) * s_inv[o >> 6];
        if (tid >= 500) {
            const int h = tid - 500;   // 0..11
            float m0 = s_aggr[h*3+0] - s_geo[3];
            float m1 = s_aggr[h*3+1] - s_geo[4];
            float m2 = s_aggr[h*3+2] - s_geo[5];
            const float* Rm = &s_geo[6];           // local_i = sum_j R[j][i]*m[j]
            float l0 = Rm[0]*m0 + Rm[3]*m1 + Rm[6]*m2;
            float l1 = Rm[1]*m0 + Rm[4]*m1 + Rm[7]*m2;
            float l2 = Rm[2]*m0 + Rm[5]*m1 + Rm[8]*m2;
            float dist = sqrtf(l0*l0 + l1*l1 + l2*l2);
            float idn = 1.0f/(dist + 1e-4f);
            s_f[960 + h*3+0] = l0; s_f[960 + h*3+1] = l1; s_f[960 + h*3+2] = l2;
            s_f[996 + h] = dist;
            s_f[1008 + h*3+0] = l0*idn; s_f[1008 + h*3+1] = l1*idn; s_f[1008 + h*3+2] = l2*idn;
        }
        __syncthreads();

        // ---- phase 4: output projection, 4 quarters per f ----
        {
            const int f = tid & 127, q4 = tid >> 7;
            const float* wr = Woutg + (size_t)f * FEAT;
            float acc = 0.f;
            for (int kk = q4*4; kk < FEAT; kk += 16) {
                float4 fv = *(const float4*)&s_f[kk];
                float4 wvv = *(const float4*)(wr + kk);
                acc += fv.x*wvv.x + fv.y*wvv.y + fv.z*wvv.z + fv.w*wvv.w;
            }
            s_big[q4*FF + f] = acc;
        }
        __syncthreads();
        if (tid < FF)
            s_y[tid] = s_x[tid] + boutg[tid]
                     + s_big[tid] + s_big[FF + tid] + s_big[2*FF + tid] + s_big[3*FF + tid];
    } else {
        if (tid < FF) s_y[tid] = s_x[tid];
    }
    __syncthreads();

    // ---- LayerNorm ----
    if (tid < 64) {
        float a = s_y[tid], b = s_y[tid + 64];
        float s1 = a + b, s2 = a*a + b*b;
        #pragma unroll
        for (int off = 32; off > 0; off >>= 1) {
            s1 += __shfl_xor(s1, off, 64);
            s2 += __shfl_xor(s2, off, 64);
        }
        if (tid == 0) { s_red[0] = s1; s_red[1] = s2; }
    }
    __syncthreads();
    if (tid < FF) {
        float mu  = s_red[0] * (1.0f/FF);
        float var = s_red[1] * (1.0f/FF) - mu*mu;
        float vv = (s_y[tid] - mu) * rsqrtf(fmaxf(var, 0.0f) + 1e-5f);
        vv = vv * lnwg[tid] + lnbg[tid];
        outg[(size_t)row*FF + tid] = vv;
    }
}

extern "C" void kernel_launch(void* const* d_in, const int* in_sizes, int n_in,
                              void* d_out, int out_size, void* d_ws, size_t ws_size,
                              hipStream_t stream) {
    const float* Rg    = (const float*)d_in[0];
    const float* tg    = (const float*)d_in[1];
    const float* pg    = (const float*)d_in[2];
    const float* xg    = (const float*)d_in[3];
    const float* zg    = (const float*)d_in[4];
    const int*   maskg = (const int*)d_in[5];
    const float* Wq    = (const float*)d_in[6];
    const float* Wk    = (const float*)d_in[7];
    const float* Wv    = (const float*)d_in[8];
    const float* Wpb   = (const float*)d_in[9];
    const float* gam   = (const float*)d_in[10];
    const float* Wout  = (const float*)d_in[11];
    const float* bout  = (const float*)d_in[12];
    const float* lnw   = (const float*)d_in[13];
    const float* lnb   = (const float*)d_in[14];
    float* outp = (float*)d_out;

    float* q_ws = (float*)d_ws;
    float* kT4  = q_ws + (size_t)NB*LL*HD;
    float* vT   = kT4  + (size_t)NB*LL*HD;

    qkv_kernel<<<NB*LL, HD, 0, stream>>>(xg, Wq, Wk, Wv, q_ws, kT4, vT);
    attn_kernel<<<NB*LL, 512, 0, stream>>>(Rg, tg, pg, xg, zg, maskg,
                                           Wpb, gam, Wout, bout, lnw, lnb,
                                           q_ws, kT4, vT, outp);
}

// Round 12
// 324.534 us; speedup vs baseline: 1.1650x; 1.1650x over previous
//
#include <hip/hip_runtime.h>
#include <hip/hip_bf16.h>

constexpr int NB   = 2;
constexpr int LL   = 512;
constexpr int FF   = 128;
constexpr int CC   = 64;
constexpr int HH   = 12;
constexpr int DD   = 16;
constexpr int HD   = HH * DD;      // 192
constexpr int FEAT = HH*CC + HH*DD + HH*7;  // 1044
constexpr float INFV   = 100000.0f;
constexpr float SCALEF = 0.57735026918962576f;   // sqrt(1/3)
constexpr float SQ29H  = 0.23570226039551584f;   // sqrt(2/9)/2

// ---------------- kernel 1: q/k/v projections, W streamed via LDS ----------------
// k stored as kT4[n][hd/4][j][4] -> phase-1 reads one coalesced dwordx4 per hd4.
// v stored transposed vT[n][hd][j] (phase-2a float4 along j).
__global__ __launch_bounds__(192) void qkv_kernel(
    const float* __restrict__ xg, const float* __restrict__ Wq,
    const float* __restrict__ Wk, const float* __restrict__ Wv,
    float* __restrict__ q_ws, float* __restrict__ kT4, float* __restrict__ vT)
{
    const int row = blockIdx.x;
    const int n = row >> 9, i = row & 511;
    const int t = threadIdx.x;
    __shared__ __align__(16) float sx[FF];
    __shared__ __align__(16) float sw[3*HD*20];   // 45 KB

    if (t < FF) sx[t] = xg[(size_t)row*FF + t];

    float aq = 0.f, ak = 0.f, av = 0.f;
    for (int ft = 0; ft < 8; ++ft) {
        __syncthreads();
        #pragma unroll
        for (int m = 0; m < 3; ++m) {
            const float* W = (m == 0) ? Wq : ((m == 1) ? Wk : Wv);
            #pragma unroll
            for (int p = 0; p < 4; ++p) {
                const int r = (t >> 2) + 48*p, q = t & 3;
                float4 v = *(const float4*)(W + (size_t)r*FF + ft*16 + q*4);
                *(float4*)&sw[m*3840 + r*20 + q*4] = v;
            }
        }
        __syncthreads();
        const float* xf = &sx[ft*16];
        const float* wq = &sw[0*3840 + t*20];
        const float* wk = &sw[1*3840 + t*20];
        const float* wv = &sw[2*3840 + t*20];
        #pragma unroll
        for (int f4 = 0; f4 < 4; ++f4) {
            float4 xv = *(const float4*)&xf[f4*4];
            float4 a = *(const float4*)&wq[f4*4];
            float4 b = *(const float4*)&wk[f4*4];
            float4 c = *(const float4*)&wv[f4*4];
            aq += xv.x*a.x + xv.y*a.y + xv.z*a.z + xv.w*a.w;
            ak += xv.x*b.x + xv.y*b.y + xv.z*b.z + xv.w*b.w;
            av += xv.x*c.x + xv.y*c.y + xv.z*c.z + xv.w*c.w;
        }
    }
    q_ws[(size_t)row*HD + t] = aq;
    kT4[(((size_t)n*48 + (t >> 2))*LL + i)*4 + (t & 3)] = ak;
    vT[((size_t)n*HD + t)*LL + i] = av;
}

// ---------------- kernel 2: fused attention, 512 threads/block ----------------
// = round 10 kernel (146 µs, VGPR 40) with ONLY the kT4 phase-1 read change.
__global__ __launch_bounds__(512, 2) void attn_kernel(
    const float* __restrict__ Rg, const float* __restrict__ tg, const float* __restrict__ pg,
    const float* __restrict__ xg, const float* __restrict__ zg, const int* __restrict__ maskg,
    const float* __restrict__ Wpbg, const float* __restrict__ gammag,
    const float* __restrict__ Woutg, const float* __restrict__ boutg,
    const float* __restrict__ lnwg, const float* __restrict__ lnbg,
    const float* __restrict__ q_ws, const float* __restrict__ kT4, const float* __restrict__ vT,
    float* __restrict__ outg)
{
    const int row = blockIdx.x;          // n*LL + i
    const int n = row >> 9;
    const int tid = threadIdx.x;

    __shared__ __align__(16) float s_exp[HH*LL];   // 24 KB  exp(logits), h-major
    __shared__ __align__(16) float s_big[4*768];   // 12 KB  wpb (phase1) / 2b partials / p4 partials
    __shared__ __align__(16) float s_q[HD];
    __shared__ __align__(16) float s_x[FF];
    __shared__ __align__(16) float s_y[FF];
    __shared__ __align__(16) float s_f[FEAT];
    __shared__ float s_aggr[36];
    __shared__ float s_inv[HH];
    __shared__ float s_coef[HH];
    __shared__ float s_geo[15];   // p_i[3], t[3], R[9]
    __shared__ float s_red[2];

    if (tid < FF) s_x[tid] = xg[(size_t)row*FF + tid];
    if (tid >= 128 && tid < 128 + HD) s_q[tid-128] = q_ws[(size_t)row*HD + (tid-128)];
    for (int o = tid; o < HH*CC; o += 512) s_big[o] = Wpbg[o];   // wpb staged in s_big
    if (tid >= 320 && tid < 332) {
        float g = gammag[tid-320];
        float gamma = log1pf(__expf(fminf(g, 80.0f)));   // softplus
        s_coef[tid-320] = -gamma * SQ29H;
    }
    if (tid >= 332 && tid < 335) s_geo[tid-332] = pg[(size_t)row*3 + (tid-332)];
    if (tid >= 335 && tid < 338) s_geo[3 + tid-335] = tg[(size_t)row*3 + (tid-335)];
    if (tid >= 338 && tid < 347) s_geo[6 + tid-338] = Rg[(size_t)row*9 + (tid-338)];
    const int mi = maskg[row];   // block-uniform
    __syncthreads();

    if (mi) {
        // ---- phase 1: exp(logits), one j per thread; acc[12], z read ONCE ----
        {
            const int j = tid;
            float acc[HH];
            #pragma unroll
            for (int h = 0; h < HH; ++h) acc[h] = 0.f;

            // z . Wpb : z chunk consumed immediately against LDS broadcasts
            const float* zr = zg + ((size_t)row*LL + j)*CC;
            #pragma unroll
            for (int c4 = 0; c4 < CC/4; ++c4) {
                float4 zv = *(const float4*)(zr + c4*4);
                #pragma unroll
                for (int h = 0; h < HH; ++h) {
                    float4 w = *(const float4*)&s_big[h*CC + c4*4];   // broadcast
                    acc[h] += zv.x*w.x + zv.y*w.y + zv.z*w.z + zv.w*w.w;
                }
            }
            // q . k : kT4 -> one coalesced dwordx4 per hd4 (48 total, was 192 b32)
            const float* kb = kT4 + ((size_t)(n*48)*LL + j)*4;
            #pragma unroll
            for (int hd4 = 0; hd4 < HD/4; ++hd4) {
                float4 q4 = *(const float4*)&s_q[hd4*4];
                float4 k4 = *(const float4*)(kb + (size_t)hd4*LL*4);
                acc[hd4 >> 2] += q4.x*k4.x + q4.y*k4.y + q4.z*k4.z + q4.w*k4.w;
            }
            const float* pj = pg + ((size_t)n*LL + j)*3;
            float e0 = s_geo[0]-pj[0];
            float e1 = s_geo[1]-pj[1];
            float e2 = s_geo[2]-pj[2];
            float d2 = e0*e0 + e1*e1 + e2*e2;
            const float sub = maskg[n*LL + j] ? 0.0f : INFV;
            #pragma unroll
            for (int h = 0; h < HH; ++h) {
                float lg = (acc[h] + d2*s_coef[h]) * SCALEF - sub;
                s_exp[h*LL + j] = __expf(fminf(lg, 80.0f));
            }
        }
        __syncthreads();

        // ---- per-head sums -> reciprocals ----
        {
            const int wv = tid >> 6, lane = tid & 63;
            for (int h = wv; h < HH; h += 8) {
                float s = 0.f;
                #pragma unroll
                for (int r = 0; r < 8; ++r) s += s_exp[h*LL + lane + (r<<6)];
                #pragma unroll
                for (int off = 32; off > 0; off >>= 1) s += __shfl_xor(s, off, 64);
                if (lane == 0) s_inv[h] = 1.0f / fmaxf(s, 1e-30f);
            }
        }
        __syncthreads();

        // ---- phases 2a + 2b CONCURRENT on disjoint waves (r10 versions) ----
        {
            const int wv = tid >> 6, lane = tid & 63;
            if (wv < 4) {
                // 2b: feat_p2n partials; wave q4v = j-chunk of 128, lane = c (scalar ep reads)
                const int c = lane, q4v = wv;
                float acc[HH];
                #pragma unroll
                for (int h = 0; h < HH; ++h) acc[h] = 0.f;
                const float* zb = zg + ((size_t)row*LL + q4v*128)*CC + c;
                const float* ep = s_exp + q4v*128;
                #pragma unroll 2
                for (int jj = 0; jj < 128; ++jj) {
                    float zv = zb[(size_t)jj*CC];
                    #pragma unroll
                    for (int h = 0; h < HH; ++h) acc[h] += ep[h*LL + jj] * zv;
                }
                #pragma unroll
                for (int h = 0; h < HH; ++h) s_big[q4v*768 + h*64 + c] = acc[h];
            } else if (tid < 448) {
                // 2a: feat_node, hd = tid-256, full-j float4 (vT)
                const int hd = tid - 256;
                const float* vb = vT + ((size_t)n*HD + hd)*LL;
                const float* ep = s_exp + (hd >> 4)*LL;
                float a = 0.f;
                #pragma unroll 2
                for (int j4 = 0; j4 < 128; ++j4) {
                    float4 vv = *(const float4*)(vb + j4*4);
                    float4 av = *(const float4*)(ep + j4*4);
                    a += vv.x*av.x + vv.y*av.y + vv.z*av.z + vv.w*av.w;
                }
                s_f[768 + hd] = a * s_inv[hd >> 4];
            } else {
                // alpha . p_CB: 36 outputs on wave 7
                const int o = tid - 448;
                if (o < 36) {
                    const int h = o / 3, ax = o - h*3;
                    const float* pb = pg + (size_t)n*LL*3 + ax;
                    const float* ep = s_exp + h*LL;
                    float a = 0.f;
                    #pragma unroll 4
                    for (int j = 0; j < LL; ++j) a += ep[j] * pb[(size_t)j*3];
                    s_aggr[o] = a * s_inv[h];
                }
            }
        }
        __syncthreads();

        // ---- 2b reduce + phase 3 ----
        for (int o = tid; o < 768; o += 512)
            s_f[o] = (s_big[o] + s_big[768+o] + s_big[1536+o] + s_big[2304+o]) * s_inv[o >> 6];
        if (tid >= 500) {
            const int h = tid - 500;   // 0..11
            float m0 = s_aggr[h*3+0] - s_geo[3];
            float m1 = s_aggr[h*3+1] - s_geo[4];
            float m2 = s_aggr[h*3+2] - s_geo[5];
            const float* Rm = &s_geo[6];           // local_i = sum_j R[j][i]*m[j]
            float l0 = Rm[0]*m0 + Rm[3]*m1 + Rm[6]*m2;
            float l1 = Rm[1]*m0 + Rm[4]*m1 + Rm[7]*m2;
            float l2 = Rm[2]*m0 + Rm[5]*m1 + Rm[8]*m2;
            float dist = sqrtf(l0*l0 + l1*l1 + l2*l2);
            float idn = 1.0f/(dist + 1e-4f);
            s_f[960 + h*3+0] = l0; s_f[960 + h*3+1] = l1; s_f[960 + h*3+2] = l2;
            s_f[996 + h] = dist;
            s_f[1008 + h*3+0] = l0*idn; s_f[1008 + h*3+1] = l1*idn; s_f[1008 + h*3+2] = l2*idn;
        }
        __syncthreads();

        // ---- phase 4: output projection, 4 quarters per f ----
        {
            const int f = tid & 127, q4 = tid >> 7;
            const float* wr = Woutg + (size_t)f * FEAT;
            float acc = 0.f;
            for (int kk = q4*4; kk < FEAT; kk += 16) {
                float4 fv = *(const float4*)&s_f[kk];
                float4 wvv = *(const float4*)(wr + kk);
                acc += fv.x*wvv.x + fv.y*wvv.y + fv.z*wvv.z + fv.w*wvv.w;
            }
            s_big[q4*FF + f] = acc;
        }
        __syncthreads();
        if (tid < FF)
            s_y[tid] = s_x[tid] + boutg[tid]
                     + s_big[tid] + s_big[FF + tid] + s_big[2*FF + tid] + s_big[3*FF + tid];
    } else {
        if (tid < FF) s_y[tid] = s_x[tid];
    }
    __syncthreads();

    // ---- LayerNorm ----
    if (tid < 64) {
        float a = s_y[tid], b = s_y[tid + 64];
        float s1 = a + b, s2 = a*a + b*b;
        #pragma unroll
        for (int off = 32; off > 0; off >>= 1) {
            s1 += __shfl_xor(s1, off, 64);
            s2 += __shfl_xor(s2, off, 64);
        }
        if (tid == 0) { s_red[0] = s1; s_red[1] = s2; }
    }
    __syncthreads();
    if (tid < FF) {
        float mu  = s_red[0] * (1.0f/FF);
        float var = s_red[1] * (1.0f/FF) - mu*mu;
        float vv = (s_y[tid] - mu) * rsqrtf(fmaxf(var, 0.0f) + 1e-5f);
        vv = vv * lnwg[tid] + lnbg[tid];
        outg[(size_t)row*FF + tid] = vv;
    }
}

extern "C" void kernel_launch(void* const* d_in, const int* in_sizes, int n_in,
                              void* d_out, int out_size, void* d_ws, size_t ws_size,
                              hipStream_t stream) {
    const float* Rg    = (const float*)d_in[0];
    const float* tg    = (const float*)d_in[1];
    const float* pg    = (const float*)d_in[2];
    const float* xg    = (const float*)d_in[3];
    const float* zg    = (const float*)d_in[4];
    const int*   maskg = (const int*)d_in[5];
    const float* Wq    = (const float*)d_in[6];
    const float* Wk    = (const float*)d_in[7];
    const float* Wv    = (const float*)d_in[8];
    const float* Wpb   = (const float*)d_in[9];
    const float* gam   = (const float*)d_in[10];
    const float* Wout  = (const float*)d_in[11];
    const float* bout  = (const float*)d_in[12];
    const float* lnw   = (const float*)d_in[13];
    const float* lnb   = (const float*)d_in[14];
    float* outp = (float*)d_out;

    float* q_ws = (float*)d_ws;
    float* kT4  = q_ws + (size_t)NB*LL*HD;
    float* vT   = kT4  + (size_t)NB*LL*HD;

    qkv_kernel<<<NB*LL, HD, 0, stream>>>(xg, Wq, Wk, Wv, q_ws, kT4, vT);
    attn_kernel<<<NB*LL, 512, 0, stream>>>(Rg, tg, pg, xg, zg, maskg,
                                           Wpb, gam, Wout, bout, lnw, lnb,
                                           q_ws, kT4, vT, outp);
}